// Round 5
// baseline (254.559 us; speedup 1.0000x reference)
//
#include <hip/hip_runtime.h>
#include <math.h>

#define NROWS 2000000
#define IN_DIM 64
#define HID 128
#define NTILES (NROWS / 16)   // 125000 tiles of 16 rows
#define BLOCK 256
#define NBLK 1024             // 4 blocks/CU x 256 CU
#define WPB (BLOCK / 64)      // 4 waves per block

typedef _Float16 half8 __attribute__((ext_vector_type(8)));
typedef float f32x4 __attribute__((ext_vector_type(4)));

// tanh(a) = 1 - 2/(exp(2a)+1); NaN-free as a -> +/-inf (exp->inf, rcp->0)
__device__ __forceinline__ float tanh_fast(float a) {
    float p = __expf(2.0f * a);
    float r = __builtin_amdgcn_rcpf(p + 1.0f);
    return fmaf(-2.0f, r, 1.0f);
}

// Sum within each 16-lane group on the VALU pipe (v_add + DPP row_shr).
// After the chain, lane (c16==15) of each group holds the 16-lane total.
// bound_ctrl=1 -> shifted-in lanes read 0. NO LDS/DS-pipe traffic.
__device__ __forceinline__ float dpp_row_sum16(float v) {
    int x;
    x = __float_as_int(v);
    v += __int_as_float(__builtin_amdgcn_update_dpp(0, x, 0x111, 0xf, 0xf, true)); // shr:1
    x = __float_as_int(v);
    v += __int_as_float(__builtin_amdgcn_update_dpp(0, x, 0x112, 0xf, 0xf, true)); // shr:2
    x = __float_as_int(v);
    v += __int_as_float(__builtin_amdgcn_update_dpp(0, x, 0x114, 0xf, 0xf, true)); // shr:4
    x = __float_as_int(v);
    v += __int_as_float(__builtin_amdgcn_update_dpp(0, x, 0x118, 0xf, 0xf, true)); // shr:8
    return v;
}

__global__ void zero_sums_kernel(float* g) {
    if (threadIdx.x < 2) g[threadIdx.x] = 0.0f;
}

// launch_bounds 2nd arg is MIN BLOCKS/CU under hipcc (round-3 evidence:
// (512,4) forced a 64-reg cap = 32 waves/CU). (256,4): 4 blk x 4 waves =
// 16 waves/CU = 4/SIMD -> 128-reg cap; est. live set ~105 -> no spill.
__global__ __launch_bounds__(BLOCK, 4) void fused_mfma_kernel(
    const float* __restrict__ x, const int* __restrict__ T,
    const float* __restrict__ W1, const float* __restrict__ b1,
    const float* __restrict__ W2, const float* __restrict__ b2,
    float* __restrict__ e_out, float* __restrict__ gsums)
{
    // W1 as fp16 B-fragments, shared by all waves: [t][c][lane][8] = 16 KB
    __shared__ _Float16 wlds[8][2][64][8];

    const int lane = threadIdx.x & 63;
    const int wv   = threadIdx.x >> 6;
    const int c16  = lane & 15;   // A-row / B-col residue
    const int g4   = lane >> 4;   // k-octet / C row-group

    // ---- one-time: build W1 fp16 fragments in LDS (wave wv handles 2 t's) ----
    #pragma unroll
    for (int tt = 0; tt < 2; tt++) {
        const int t = wv * 2 + tt;
        const int n = t * 16 + c16;
        #pragma unroll
        for (int c = 0; c < 2; c++) {
            const int kb = c * 32 + g4 * 8;
            half8 h;
            #pragma unroll
            for (int j = 0; j < 8; j++)
                h[j] = (_Float16)W1[n * IN_DIM + kb + j];
            *(half8*)&wlds[t][c][lane][0] = h;
        }
    }
    __syncthreads();   // only barrier; wlds is read-only afterwards

    float b1v[8], w2v[8];
    #pragma unroll
    for (int t = 0; t < 8; t++) {
        b1v[t] = b1[t * 16 + c16];
        w2v[t] = W2[t * 16 + c16];
    }
    const float b2v = b2[0];

    const int gwave = blockIdx.x * WPB + wv;
    const int nwave = NBLK * WPB;     // 4096 waves, all resident

    float ls0 = 0.f, ls1 = 0.f;

    // ---- 1-deep prefetch: A-frag source, row = tile*16 + c16, k = g4*8 (+32) ----
    int tile = gwave;
    f32x4 g0, g1, g2, g3;
    {
        const float* xp = x + (size_t)tile * 1024 + (size_t)c16 * IN_DIM + g4 * 8;
        g0 = *(const f32x4*)(xp);
        g1 = *(const f32x4*)(xp + 4);
        g2 = *(const f32x4*)(xp + 32);
        g3 = *(const f32x4*)(xp + 36);
    }

    for (; tile < NTILES; tile += nwave) {
        // convert staged f32 -> fp16 A-fragments (consumes g0..g3)
        half8 xf0, xf1;
        #pragma unroll
        for (int j = 0; j < 4; j++) {
            xf0[j]     = (_Float16)g0[j];
            xf0[4 + j] = (_Float16)g1[j];
            xf1[j]     = (_Float16)g2[j];
            xf1[4 + j] = (_Float16)g3[j];
        }

        // issue next tile's loads immediately (use-distance ~= 1 full iteration;
        // 16 waves/CU x 4 KB in flight >> 9.2 KB needed to cover HBM latency)
        const int nt = tile + nwave;
        if (nt < NTILES) {
            const float* xp = x + (size_t)nt * 1024 + (size_t)c16 * IN_DIM + g4 * 8;
            g0 = *(const f32x4*)(xp);
            g1 = *(const f32x4*)(xp + 4);
            g2 = *(const f32x4*)(xp + 32);
            g3 = *(const f32x4*)(xp + 36);
        }

        // ---- h = x @ W1.T : 16 fp16 MFMAs, W frags streamed from LDS ----
        f32x4 acc[8];
        #pragma unroll
        for (int t = 0; t < 8; t++) acc[t] = (f32x4){0.f, 0.f, 0.f, 0.f};
        #pragma unroll
        for (int t = 0; t < 8; t++) {
            half8 w0 = *(const half8*)&wlds[t][0][lane][0];
            half8 w1 = *(const half8*)&wlds[t][1][lane][0];
            acc[t] = __builtin_amdgcn_mfma_f32_16x16x32_f16(xf0, w0, acc[t], 0, 0, 0);
            acc[t] = __builtin_amdgcn_mfma_f32_16x16x32_f16(xf1, w1, acc[t], 0, 0, 0);
        }

        // ---- epilogue: bias + tanh + W2 partials (all VALU/trans, no DS) ----
        // C layout: lane holds h[row = g4*4 + r][col = t*16 + c16]
        float sp0 = 0.f, sp1 = 0.f, sp2 = 0.f, sp3 = 0.f;
        #pragma unroll
        for (int t = 0; t < 8; t++) {
            sp0 = fmaf(tanh_fast(acc[t][0] + b1v[t]), w2v[t], sp0);
            sp1 = fmaf(tanh_fast(acc[t][1] + b1v[t]), w2v[t], sp1);
            sp2 = fmaf(tanh_fast(acc[t][2] + b1v[t]), w2v[t], sp2);
            sp3 = fmaf(tanh_fast(acc[t][3] + b1v[t]), w2v[t], sp3);
        }
        // sum over the 16 col-residue lanes via DPP (VALU pipe, zero DS ops)
        sp0 = dpp_row_sum16(sp0);
        sp1 = dpp_row_sum16(sp1);
        sp2 = dpp_row_sum16(sp2);
        sp3 = dpp_row_sum16(sp3);

        if (c16 == 15) {   // 4 lanes/wave; each owns 4 consecutive rows
            const int row0 = tile * 16 + g4 * 4;
            float e0 = __expf(sp0 + b2v);
            float e1 = __expf(sp1 + b2v);
            float e2 = __expf(sp2 + b2v);
            float e3 = __expf(sp3 + b2v);
            *(f32x4*)&e_out[row0] = (f32x4){e0, e1, e2, e3};
            int4 t4 = *(const int4*)&T[row0];
            if (t4.x == 0) ls0 += e0; else ls1 += e0;
            if (t4.y == 0) ls0 += e1; else ls1 += e1;
            if (t4.z == 0) ls0 += e2; else ls1 += e2;
            if (t4.w == 0) ls0 += e3; else ls1 += e3;
        }
    }

    // per-wave reduce, then one atomic pair per wave (4096 waves total)
    #pragma unroll
    for (int off = 32; off > 0; off >>= 1) {
        ls0 += __shfl_down(ls0, off, 64);
        ls1 += __shfl_down(ls1, off, 64);
    }
    if (lane == 0) {
        atomicAdd(&gsums[0], ls0);
        atomicAdd(&gsums[1], ls1);
    }
}

__global__ __launch_bounds__(256) void normalize_kernel(
    float* __restrict__ e_out, const int* __restrict__ T,
    const float* __restrict__ gsums)
{
    const float inv0 = 1.0f / gsums[0];
    const float inv1 = 1.0f / gsums[1];
    const int n4 = NROWS / 4;
    const int stride = gridDim.x * blockDim.x;
    for (int i = blockIdx.x * blockDim.x + threadIdx.x; i < n4; i += stride) {
        float4 e = reinterpret_cast<const float4*>(e_out)[i];
        int4  t = reinterpret_cast<const int4*>(T)[i];
        e.x *= (t.x == 0) ? inv0 : inv1;
        e.y *= (t.y == 0) ? inv0 : inv1;
        e.z *= (t.z == 0) ? inv0 : inv1;
        e.w *= (t.w == 0) ? inv0 : inv1;
        reinterpret_cast<float4*>(e_out)[i] = e;
    }
}

extern "C" void kernel_launch(void* const* d_in, const int* in_sizes, int n_in,
                              void* d_out, int out_size, void* d_ws, size_t ws_size,
                              hipStream_t stream) {
    const float* x  = (const float*)d_in[0];
    const int*   T  = (const int*)d_in[1];
    const float* W1 = (const float*)d_in[2];
    const float* b1 = (const float*)d_in[3];
    const float* W2 = (const float*)d_in[4];
    const float* b2 = (const float*)d_in[5];
    float* e_out = (float*)d_out;
    float* gsums = (float*)d_ws;

    zero_sums_kernel<<<1, 64, 0, stream>>>(gsums);

    // 1024 blocks x 256 thr = 4096 waves; 16 KB LDS, <=128 VGPR ->
    // 4 blocks/CU, 16 waves/CU (4/SIMD), all resident.
    fused_mfma_kernel<<<NBLK, BLOCK, 0, stream>>>(x, T, W1, b1, W2, b2, e_out, gsums);

    normalize_kernel<<<2048, 256, 0, stream>>>(e_out, T, gsums);
}

// Round 6
// 179.120 us; speedup vs baseline: 1.4212x; 1.4212x over previous
//
#include <hip/hip_runtime.h>
#include <math.h>

#define NROWS 2000000
#define IN_DIM 64
#define HID 128
#define NTILES (NROWS / 16)   // 125000 tiles of 16 rows
#define BLOCK 256
#define NBLK 768              // 3 blocks/CU x 256 CU
#define WPB (BLOCK / 64)      // 4 waves per block

typedef _Float16 half8 __attribute__((ext_vector_type(8)));
typedef float f32x4 __attribute__((ext_vector_type(4)));

// tanh(a) = 1 - 2/(exp(2a)+1); NaN-free as a -> +/-inf
__device__ __forceinline__ float tanh_fast(float a) {
    float p = __expf(2.0f * a);
    float r = __builtin_amdgcn_rcpf(p + 1.0f);
    return fmaf(-2.0f, r, 1.0f);
}

// Sum within each 16-lane group on the VALU pipe (v_add + DPP row_shr).
// Lane (c16==15) of each group ends with the total. Zero DS-pipe traffic.
__device__ __forceinline__ float dpp_row_sum16(float v) {
    int x;
    x = __float_as_int(v);
    v += __int_as_float(__builtin_amdgcn_update_dpp(0, x, 0x111, 0xf, 0xf, true));
    x = __float_as_int(v);
    v += __int_as_float(__builtin_amdgcn_update_dpp(0, x, 0x112, 0xf, 0xf, true));
    x = __float_as_int(v);
    v += __int_as_float(__builtin_amdgcn_update_dpp(0, x, 0x114, 0xf, 0xf, true));
    x = __float_as_int(v);
    v += __int_as_float(__builtin_amdgcn_update_dpp(0, x, 0x118, 0xf, 0xf, true));
    return v;
}

// DMA one 4KB x-tile into per-wave LDS buffer.
// LDS dest is LINEAR (HW: wave-uniform base + lane*16). Global SOURCE is
// XOR-swizzled per 16B chunk: slot (row r, col cs) pulls global chunk
// (r, cs ^ (r&7)). Self-inverse; readers apply the same XOR. The XOR stays
// within each 128B half-line (bit3 untouched) -> fetch stays line-perfect.
__device__ __forceinline__ void dma_tile(const float* __restrict__ xsrc,
                                         char* dst, int lane) {
    #pragma unroll
    for (int k = 0; k < 4; k++) {
        const int slot = k * 64 + lane;          // 16B-chunk index in [0,256)
        const int r = slot >> 4, cs = slot & 15;
        const int srcc = (r << 4) | (cs ^ (r & 7));
        __builtin_amdgcn_global_load_lds(
            (const __attribute__((address_space(1))) void*)(xsrc + srcc * 4),
            (__attribute__((address_space(3))) void*)(dst + k * 1024),
            16, 0, 0);
    }
}

__global__ void zero_sums_kernel(float* g) {
    if (threadIdx.x < 2) g[threadIdx.x] = 0.0f;
}

// (256,3): 3 blocks/CU x 4 waves = 12 waves/CU = 3/SIMD -> ~170-reg cap
// (round-3 evidence: 2nd arg is min BLOCKS/CU). Est. live set ~150 -> no spill.
__global__ __launch_bounds__(BLOCK, 3) void fused_mfma_kernel(
    const float* __restrict__ x, const int* __restrict__ T,
    const float* __restrict__ W1, const float* __restrict__ b1,
    const float* __restrict__ W2, const float* __restrict__ b2,
    float* __restrict__ e_out, float* __restrict__ gsums)
{
    // per-wave x double buffer: 4 waves x 2 x 4KB = 32 KB/block
    __shared__ char xbuf[WPB][2][4096];

    const int lane = threadIdx.x & 63;
    const int wv   = threadIdx.x >> 6;
    const int c16  = lane & 15;   // A-row / C-col residue
    const int g4   = lane >> 4;   // k-octet / C row-group

    // ---- W1 as fp16 B-fragments in REGISTERS (16 x half8 = 64 VGPR) ----
    // B[k][n] = W1[n][k]; lane: n = t*16 + c16, k = c*32 + g4*8 + j
    half8 wreg[8][2];
    #pragma unroll
    for (int t = 0; t < 8; t++) {
        const int n = t * 16 + c16;
        #pragma unroll
        for (int c = 0; c < 2; c++) {
            const float* wp = W1 + n * IN_DIM + c * 32 + g4 * 8;
            half8 h;
            #pragma unroll
            for (int j = 0; j < 8; j++) h[j] = (_Float16)wp[j];
            wreg[t][c] = h;
        }
    }
    float b1v[8], w2v[8];
    #pragma unroll
    for (int t = 0; t < 8; t++) {
        b1v[t] = b1[t * 16 + c16];
        w2v[t] = W2[t * 16 + c16];
    }
    const float b2v = b2[0];

    char* bufA = &xbuf[wv][0][0];
    char* bufB = &xbuf[wv][1][0];

    const int gwave = blockIdx.x * WPB + wv;
    const int nwave = NBLK * WPB;     // 3072 waves, all resident

    float ls0 = 0.f, ls1 = 0.f;

    int tile = gwave;
    if (tile < NTILES) dma_tile(x + (size_t)tile * 1024, bufA, lane);

    // reader offsets (swizzled): row c16, global cols {2g4, 2g4+1, +8, +9}
    const int c7 = c16 & 7;
    const int col0 = (2 * g4) ^ c7;
    const int col1 = (2 * g4 + 1) ^ c7;
    const int rb = c16 * 256;
    const int o0 = rb + col0 * 16;
    const int o1 = rb + col1 * 16;
    const int o2 = rb + (col0 + 8) * 16;   // bit3 untouched by XOR (c7<8)
    const int o3 = rb + (col1 + 8) * 16;

    for (; tile < NTILES; tile += nwave) {
        // current tile's DMA (issued one iteration ago) must have landed
        asm volatile("s_waitcnt vmcnt(0)" ::: "memory");

        f32x4 a0 = *(const f32x4*)(bufA + o0);
        f32x4 a1 = *(const f32x4*)(bufA + o1);
        f32x4 a2 = *(const f32x4*)(bufA + o2);
        f32x4 a3 = *(const f32x4*)(bufA + o3);

        // issue next tile's DMA into the other buffer (overlaps all compute)
        const int nt = tile + nwave;
        if (nt < NTILES) dma_tile(x + (size_t)nt * 1024, bufB, lane);

        // f32 -> fp16 A-fragments
        half8 xf0, xf1;
        #pragma unroll
        for (int j = 0; j < 4; j++) {
            xf0[j]     = (_Float16)a0[j];
            xf0[4 + j] = (_Float16)a1[j];
            xf1[j]     = (_Float16)a2[j];
            xf1[4 + j] = (_Float16)a3[j];
        }

        // ---- h = x @ W1.T : 16 fp16 MFMAs, W from registers ----
        f32x4 acc[8];
        #pragma unroll
        for (int t = 0; t < 8; t++) acc[t] = (f32x4){0.f, 0.f, 0.f, 0.f};
        #pragma unroll
        for (int t = 0; t < 8; t++) {
            acc[t] = __builtin_amdgcn_mfma_f32_16x16x32_f16(xf0, wreg[t][0], acc[t], 0, 0, 0);
            acc[t] = __builtin_amdgcn_mfma_f32_16x16x32_f16(xf1, wreg[t][1], acc[t], 0, 0, 0);
        }

        // ---- epilogue: bias + tanh + W2 partials (VALU/trans only) ----
        // C layout: lane holds h[row = g4*4 + r][col = t*16 + c16]
        float sp0 = 0.f, sp1 = 0.f, sp2 = 0.f, sp3 = 0.f;
        #pragma unroll
        for (int t = 0; t < 8; t++) {
            sp0 = fmaf(tanh_fast(acc[t][0] + b1v[t]), w2v[t], sp0);
            sp1 = fmaf(tanh_fast(acc[t][1] + b1v[t]), w2v[t], sp1);
            sp2 = fmaf(tanh_fast(acc[t][2] + b1v[t]), w2v[t], sp2);
            sp3 = fmaf(tanh_fast(acc[t][3] + b1v[t]), w2v[t], sp3);
        }
        sp0 = dpp_row_sum16(sp0);
        sp1 = dpp_row_sum16(sp1);
        sp2 = dpp_row_sum16(sp2);
        sp3 = dpp_row_sum16(sp3);

        if (c16 == 15) {   // 4 lanes/wave, each owns 4 consecutive rows
            const int row0 = tile * 16 + g4 * 4;
            float e0 = __expf(sp0 + b2v);
            float e1 = __expf(sp1 + b2v);
            float e2 = __expf(sp2 + b2v);
            float e3 = __expf(sp3 + b2v);
            *(f32x4*)&e_out[row0] = (f32x4){e0, e1, e2, e3};
            int4 t4 = *(const int4*)&T[row0];
            if (t4.x == 0) ls0 += e0; else ls1 += e0;
            if (t4.y == 0) ls0 += e1; else ls1 += e1;
            if (t4.z == 0) ls0 += e2; else ls1 += e2;
            if (t4.w == 0) ls0 += e3; else ls1 += e3;
        }

        // swap double buffers (pointer swap keeps indexing static)
        char* tmp = bufA; bufA = bufB; bufB = tmp;
    }

    // per-wave reduce, then one atomic pair per wave (3072 waves total)
    #pragma unroll
    for (int off = 32; off > 0; off >>= 1) {
        ls0 += __shfl_down(ls0, off, 64);
        ls1 += __shfl_down(ls1, off, 64);
    }
    if (lane == 0) {
        atomicAdd(&gsums[0], ls0);
        atomicAdd(&gsums[1], ls1);
    }
}

__global__ __launch_bounds__(256) void normalize_kernel(
    float* __restrict__ e_out, const int* __restrict__ T,
    const float* __restrict__ gsums)
{
    const float inv0 = 1.0f / gsums[0];
    const float inv1 = 1.0f / gsums[1];
    const int n4 = NROWS / 4;
    const int stride = gridDim.x * blockDim.x;
    for (int i = blockIdx.x * blockDim.x + threadIdx.x; i < n4; i += stride) {
        float4 e = reinterpret_cast<const float4*>(e_out)[i];
        int4  t = reinterpret_cast<const int4*>(T)[i];
        e.x *= (t.x == 0) ? inv0 : inv1;
        e.y *= (t.y == 0) ? inv0 : inv1;
        e.z *= (t.z == 0) ? inv0 : inv1;
        e.w *= (t.w == 0) ? inv0 : inv1;
        reinterpret_cast<float4*>(e_out)[i] = e;
    }
}

extern "C" void kernel_launch(void* const* d_in, const int* in_sizes, int n_in,
                              void* d_out, int out_size, void* d_ws, size_t ws_size,
                              hipStream_t stream) {
    const float* x  = (const float*)d_in[0];
    const int*   T  = (const int*)d_in[1];
    const float* W1 = (const float*)d_in[2];
    const float* b1 = (const float*)d_in[3];
    const float* W2 = (const float*)d_in[4];
    const float* b2 = (const float*)d_in[5];
    float* e_out = (float*)d_out;
    float* gsums = (float*)d_ws;

    zero_sums_kernel<<<1, 64, 0, stream>>>(gsums);

    // 768 blocks x 256 thr = 3072 waves; 32 KB LDS, ~150 VGPR ->
    // 3 blocks/CU, 12 waves/CU (3/SIMD), all resident.
    fused_mfma_kernel<<<NBLK, BLOCK, 0, stream>>>(x, T, W1, b1, W2, b2, e_out, gsums);

    normalize_kernel<<<2048, 256, 0, stream>>>(e_out, T, gsums);
}

// Round 7
// 176.873 us; speedup vs baseline: 1.4392x; 1.0127x over previous
//
#include <hip/hip_runtime.h>
#include <math.h>

#define NROWS 2000000
#define IN_DIM 64
#define HID 128
#define NTILES (NROWS / 16)   // 125000 tiles of 16 rows
#define BLOCK 256
#define NBLK 768              // 3 blocks/CU x 256 CU
#define WPB (BLOCK / 64)      // 4 waves per block

typedef _Float16 half8 __attribute__((ext_vector_type(8)));
typedef float f32x4 __attribute__((ext_vector_type(4)));

#define TWO_LOG2E 2.885390081777927f   // 2*log2(e)
#define LOG2E     1.4426950408889634f

#if __has_builtin(__builtin_amdgcn_exp2f)
#define EXP2F(x) __builtin_amdgcn_exp2f(x)
#else
#define EXP2F(x) __expf((x) * 0.6931471805599453f)
#endif

// Sum within each 16-lane group on the VALU pipe (v_add + DPP row_shr).
// Lane (c16==15) of each group ends with the total. Zero DS-pipe traffic.
__device__ __forceinline__ float dpp_row_sum16(float v) {
    int x;
    x = __float_as_int(v);
    v += __int_as_float(__builtin_amdgcn_update_dpp(0, x, 0x111, 0xf, 0xf, true));
    x = __float_as_int(v);
    v += __int_as_float(__builtin_amdgcn_update_dpp(0, x, 0x112, 0xf, 0xf, true));
    x = __float_as_int(v);
    v += __int_as_float(__builtin_amdgcn_update_dpp(0, x, 0x114, 0xf, 0xf, true));
    x = __float_as_int(v);
    v += __int_as_float(__builtin_amdgcn_update_dpp(0, x, 0x118, 0xf, 0xf, true));
    return v;
}

// DMA one 4KB x-tile into per-wave LDS buffer. LDS dest LINEAR (HW rule);
// global SOURCE XOR-swizzled per 16B chunk (self-inverse, within 128B
// half-line -> line-perfect fetch). Readers apply the same XOR.
__device__ __forceinline__ void dma_tile(const float* __restrict__ xsrc,
                                         char* dst, int lane) {
    #pragma unroll
    for (int k = 0; k < 4; k++) {
        const int slot = k * 64 + lane;          // 16B-chunk index in [0,256)
        const int r = slot >> 4, cs = slot & 15;
        const int srcc = (r << 4) | (cs ^ (r & 7));
        __builtin_amdgcn_global_load_lds(
            (const __attribute__((address_space(1))) void*)(xsrc + srcc * 4),
            (__attribute__((address_space(3))) void*)(dst + k * 1024),
            16, 0, 0);
    }
}

__global__ void zero_sums_kernel(float* g) {
    if (threadIdx.x < 2) g[threadIdx.x] = 0.0f;
}

// (256,3): 3 blocks/CU x 4 waves = 12 waves/CU = 3/SIMD -> ~170-reg cap.
// Est. live set ~150 -> no spill. LDS 48KB x 3 blocks = 144KB <= 160KB.
__global__ __launch_bounds__(BLOCK, 3) void fused_mfma_kernel(
    const float* __restrict__ x, const int* __restrict__ T,
    const float* __restrict__ W1, const float* __restrict__ b1,
    const float* __restrict__ W2, const float* __restrict__ b2,
    float* __restrict__ e_out, float* __restrict__ gsums)
{
    // per-wave x TRIPLE buffer: 4 waves x 3 x 4KB = 48 KB/block
    __shared__ char xbuf[WPB][3][4096];

    const int lane = threadIdx.x & 63;
    const int wv   = threadIdx.x >> 6;
    const int c16  = lane & 15;   // A-row / C-col residue
    const int g4   = lane >> 4;   // k-octet / C row-group

    // ---- W1 as fp16 B-fragments in REGISTERS (16 x half8 = 64 VGPR) ----
    // B[k][n] = W1[n][k]; lane: n = t*16 + c16, k = c*32 + g4*8 + j
    half8 wreg[8][2];
    #pragma unroll
    for (int t = 0; t < 8; t++) {
        const int n = t * 16 + c16;
        #pragma unroll
        for (int c = 0; c < 2; c++) {
            const float* wp = W1 + n * IN_DIM + c * 32 + g4 * 8;
            half8 h;
            #pragma unroll
            for (int j = 0; j < 8; j++) h[j] = (_Float16)wp[j];
            wreg[t][c] = h;
        }
    }
    // d1[t] = 2*log2(e)*b1 ; w2 kept raw; Sconst = sum_j W2_j + b2 (lane15-valid)
    float d1v[8], w2v[8];
    float w2loc = 0.f;
    #pragma unroll
    for (int t = 0; t < 8; t++) {
        d1v[t] = TWO_LOG2E * b1[t * 16 + c16];
        w2v[t] = W2[t * 16 + c16];
        w2loc += w2v[t];
    }
    const float Sconst = dpp_row_sum16(w2loc) + b2[0];   // valid at c16==15

    char* b0 = &xbuf[wv][0][0];
    char* b1_ = &xbuf[wv][1][0];
    char* b2_ = &xbuf[wv][2][0];

    const int gwave = blockIdx.x * WPB + wv;
    const int nwave = NBLK * WPB;     // 3072 waves, all resident

    float ls0 = 0.f, ls1 = 0.f;

    // ---- depth-2 prologue ----
    int tile = gwave;
    dma_tile(x + (size_t)tile * 1024, b0, lane);               // gwave < NTILES always
    if (tile + nwave < NTILES) {
        dma_tile(x + (size_t)(tile + nwave) * 1024, b1_, lane);
        asm volatile("s_waitcnt vmcnt(4)" ::: "memory");       // b0 landed, b1 in flight
    } else {
        asm volatile("s_waitcnt vmcnt(0)" ::: "memory");       // only b0 issued
    }

    // reader offsets (swizzled): row c16, global cols {2g4, 2g4+1, +8, +9}
    const int c7 = c16 & 7;
    const int col0 = (2 * g4) ^ c7;
    const int col1 = (2 * g4 + 1) ^ c7;
    const int rb = c16 * 256;
    const int o0 = rb + col0 * 16;
    const int o1 = rb + col1 * 16;
    const int o2 = rb + (col0 + 8) * 16;   // bit3 untouched by XOR (c7<8)
    const int o3 = rb + (col1 + 8) * 16;

    for (; tile < NTILES; tile += nwave) {
        // b0 = landed current tile
        f32x4 a0 = *(const f32x4*)(b0 + o0);
        f32x4 a1 = *(const f32x4*)(b0 + o1);
        f32x4 a2 = *(const f32x4*)(b0 + o2);
        f32x4 a3 = *(const f32x4*)(b0 + o3);

        // f32 -> fp16 A-fragments
        half8 xf0, xf1;
        #pragma unroll
        for (int j = 0; j < 4; j++) {
            xf0[j]     = (_Float16)a0[j];
            xf0[4 + j] = (_Float16)a1[j];
            xf1[j]     = (_Float16)a2[j];
            xf1[4 + j] = (_Float16)a3[j];
        }

        // ---- h = x @ W1.T : 16 fp16 MFMAs, W from registers ----
        f32x4 acc[8];
        #pragma unroll
        for (int t = 0; t < 8; t++) acc[t] = (f32x4){0.f, 0.f, 0.f, 0.f};
        #pragma unroll
        for (int t = 0; t < 8; t++) {
            acc[t] = __builtin_amdgcn_mfma_f32_16x16x32_f16(xf0, wreg[t][0], acc[t], 0, 0, 0);
            acc[t] = __builtin_amdgcn_mfma_f32_16x16x32_f16(xf1, wreg[t][1], acc[t], 0, 0, 0);
        }

        // ---- epilogue: s = Sconst - 2*sum_j w2_j * rcp(exp2(2log2e*a_j + d1_j)+1)
        // 3 VALU + 2 trans per hidden value. C layout: lane holds
        // h[row = g4*4 + r][col = t*16 + c16].
        float sp0 = 0.f, sp1 = 0.f, sp2 = 0.f, sp3 = 0.f;
        #pragma unroll
        for (int t = 0; t < 8; t++) {
            float r0 = __builtin_amdgcn_rcpf(EXP2F(fmaf(acc[t][0], TWO_LOG2E, d1v[t])) + 1.0f);
            float r1 = __builtin_amdgcn_rcpf(EXP2F(fmaf(acc[t][1], TWO_LOG2E, d1v[t])) + 1.0f);
            float r2 = __builtin_amdgcn_rcpf(EXP2F(fmaf(acc[t][2], TWO_LOG2E, d1v[t])) + 1.0f);
            float r3 = __builtin_amdgcn_rcpf(EXP2F(fmaf(acc[t][3], TWO_LOG2E, d1v[t])) + 1.0f);
            sp0 = fmaf(w2v[t], r0, sp0);
            sp1 = fmaf(w2v[t], r1, sp1);
            sp2 = fmaf(w2v[t], r2, sp2);
            sp3 = fmaf(w2v[t], r3, sp3);
        }
        sp0 = dpp_row_sum16(sp0);
        sp1 = dpp_row_sum16(sp1);
        sp2 = dpp_row_sum16(sp2);
        sp3 = dpp_row_sum16(sp3);

        if (c16 == 15) {   // 4 lanes/wave, each owns 4 consecutive rows
            const int row0 = tile * 16 + g4 * 4;
            int4 t4 = *(const int4*)&T[row0];
            float e0 = EXP2F(fmaf(-2.0f * sp0, LOG2E, Sconst * LOG2E));
            float e1 = EXP2F(fmaf(-2.0f * sp1, LOG2E, Sconst * LOG2E));
            float e2 = EXP2F(fmaf(-2.0f * sp2, LOG2E, Sconst * LOG2E));
            float e3 = EXP2F(fmaf(-2.0f * sp3, LOG2E, Sconst * LOG2E));
            *(f32x4*)&e_out[row0] = (f32x4){e0, e1, e2, e3};
            if (t4.x == 0) ls0 += e0; else ls1 += e0;
            if (t4.y == 0) ls0 += e1; else ls1 += e1;
            if (t4.z == 0) ls0 += e2; else ls1 += e2;
            if (t4.w == 0) ls0 += e3; else ls1 += e3;
        }

        // ---- issue DMA for tile+2 into the free buffer, then counted wait ----
        const int nt2 = tile + 2 * nwave;
        if (nt2 < NTILES) {
            dma_tile(x + (size_t)nt2 * 1024, b2_, lane);
            // keep {store, 4 new DMA} in flight; forces tile+1's DMA landed
            asm volatile("s_waitcnt vmcnt(5)" ::: "memory");
        } else {
            // tail: nothing new issued; force tile+1's DMA landed (keep store)
            asm volatile("s_waitcnt vmcnt(1)" ::: "memory");
        }

        // rotate triple buffer
        char* tmp = b0; b0 = b1_; b1_ = b2_; b2_ = tmp;
    }

    // per-wave reduce, then one atomic pair per wave (3072 waves total)
    #pragma unroll
    for (int off = 32; off > 0; off >>= 1) {
        ls0 += __shfl_down(ls0, off, 64);
        ls1 += __shfl_down(ls1, off, 64);
    }
    if (lane == 0) {
        atomicAdd(&gsums[0], ls0);
        atomicAdd(&gsums[1], ls1);
    }
}

__global__ __launch_bounds__(256) void normalize_kernel(
    float* __restrict__ e_out, const int* __restrict__ T,
    const float* __restrict__ gsums)
{
    const float inv0 = 1.0f / gsums[0];
    const float inv1 = 1.0f / gsums[1];
    const int n4 = NROWS / 4;
    const int stride = gridDim.x * blockDim.x;
    for (int i = blockIdx.x * blockDim.x + threadIdx.x; i < n4; i += stride) {
        float4 e = reinterpret_cast<const float4*>(e_out)[i];
        int4  t = reinterpret_cast<const int4*>(T)[i];
        e.x *= (t.x == 0) ? inv0 : inv1;
        e.y *= (t.y == 0) ? inv0 : inv1;
        e.z *= (t.z == 0) ? inv0 : inv1;
        e.w *= (t.w == 0) ? inv0 : inv1;
        reinterpret_cast<float4*>(e_out)[i] = e;
    }
}

extern "C" void kernel_launch(void* const* d_in, const int* in_sizes, int n_in,
                              void* d_out, int out_size, void* d_ws, size_t ws_size,
                              hipStream_t stream) {
    const float* x  = (const float*)d_in[0];
    const int*   T  = (const int*)d_in[1];
    const float* W1 = (const float*)d_in[2];
    const float* b1 = (const float*)d_in[3];
    const float* W2 = (const float*)d_in[4];
    const float* b2 = (const float*)d_in[5];
    float* e_out = (float*)d_out;
    float* gsums = (float*)d_ws;

    zero_sums_kernel<<<1, 64, 0, stream>>>(gsums);

    // 768 blocks x 256 thr = 3072 waves; 48 KB LDS, ~150 VGPR ->
    // 3 blocks/CU, 12 waves/CU (3/SIMD), all resident.
    fused_mfma_kernel<<<NBLK, BLOCK, 0, stream>>>(x, T, W1, b1, W2, b2, e_out, gsums);

    normalize_kernel<<<2048, 256, 0, stream>>>(e_out, T, gsums);
}

// Round 8
// 174.943 us; speedup vs baseline: 1.4551x; 1.0110x over previous
//
#include <hip/hip_runtime.h>
#include <math.h>

#define NROWS 2000000
#define IN_DIM 64
#define HID 128
#define NTILES (NROWS / 16)   // 125000 tiles of 16 rows
#define BLOCK 256
#define NBLK 768              // 3 blocks/CU x 256 CU
#define WPB (BLOCK / 64)      // 4 waves per block

typedef _Float16 half8 __attribute__((ext_vector_type(8)));
typedef float f32x4 __attribute__((ext_vector_type(4)));

#define TWO_LOG2E 2.885390081777927f   // 2*log2(e)
#define LOG2E     1.4426950408889634f

#if __has_builtin(__builtin_amdgcn_exp2f)
#define EXP2F(x) __builtin_amdgcn_exp2f(x)
#else
#define EXP2F(x) __expf((x) * 0.6931471805599453f)
#endif

// Sum within each 16-lane group on the VALU pipe (v_add + DPP row_shr).
// Lane (c16==15) of each group ends with the total. Zero DS-pipe traffic.
__device__ __forceinline__ float dpp_row_sum16(float v) {
    int x;
    x = __float_as_int(v);
    v += __int_as_float(__builtin_amdgcn_update_dpp(0, x, 0x111, 0xf, 0xf, true));
    x = __float_as_int(v);
    v += __int_as_float(__builtin_amdgcn_update_dpp(0, x, 0x112, 0xf, 0xf, true));
    x = __float_as_int(v);
    v += __int_as_float(__builtin_amdgcn_update_dpp(0, x, 0x114, 0xf, 0xf, true));
    x = __float_as_int(v);
    v += __int_as_float(__builtin_amdgcn_update_dpp(0, x, 0x118, 0xf, 0xf, true));
    return v;
}

// DMA one 4KB x-tile into per-wave LDS buffer.
// ROUND-8 CHANGE: source addresses are CONSECUTIVE per instruction
// (lane l reads base + k*1024 + l*16) so the TA merges the wave into
// 128B-line transactions. Round 6/7's XOR-pre-swizzled sources made every
// 16B lane-request its own transaction -> ~3 TB/s request-rate cap.
// LDS image is therefore the LINEAR x tile (row-major 16x64 f32).
__device__ __forceinline__ void dma_tile(const float* __restrict__ xsrc,
                                         char* dst, int lane) {
    #pragma unroll
    for (int k = 0; k < 4; k++) {
        __builtin_amdgcn_global_load_lds(
            (const __attribute__((address_space(1))) void*)(xsrc + k * 256 + lane * 4),
            (__attribute__((address_space(3))) void*)(dst + k * 1024),
            16, 0, 0);
    }
}

__global__ void zero_sums_kernel(float* g) {
    if (threadIdx.x < 2) g[threadIdx.x] = 0.0f;
}

// (256,3): 3 blocks/CU x 4 waves = 12 waves/CU = 3/SIMD -> ~170-reg cap.
// Est. live set ~150 -> no spill. LDS 48KB x 3 blocks = 144KB <= 160KB.
__global__ __launch_bounds__(BLOCK, 3) void fused_mfma_kernel(
    const float* __restrict__ x, const int* __restrict__ T,
    const float* __restrict__ W1, const float* __restrict__ b1,
    const float* __restrict__ W2, const float* __restrict__ b2,
    float* __restrict__ e_out, float* __restrict__ gsums)
{
    // per-wave x TRIPLE buffer: 4 waves x 3 x 4KB = 48 KB/block
    __shared__ char xbuf[WPB][3][4096];

    const int lane = threadIdx.x & 63;
    const int wv   = threadIdx.x >> 6;
    const int c16  = lane & 15;   // A-row / C-col residue
    const int g4   = lane >> 4;   // k-octet / C row-group

    // ---- W1 as fp16 B-fragments in REGISTERS (16 x half8 = 64 VGPR) ----
    // B[k][n] = W1[n][k]; lane: n = t*16 + c16, k = c*32 + g4*8 + j
    half8 wreg[8][2];
    #pragma unroll
    for (int t = 0; t < 8; t++) {
        const int n = t * 16 + c16;
        #pragma unroll
        for (int c = 0; c < 2; c++) {
            const float* wp = W1 + n * IN_DIM + c * 32 + g4 * 8;
            half8 h;
            #pragma unroll
            for (int j = 0; j < 8; j++) h[j] = (_Float16)wp[j];
            wreg[t][c] = h;
        }
    }
    // d1[t] = 2*log2(e)*b1 ; w2 kept raw; Sconst = sum_j W2_j + b2 (lane15-valid)
    float d1v[8], w2v[8];
    float w2loc = 0.f;
    #pragma unroll
    for (int t = 0; t < 8; t++) {
        d1v[t] = TWO_LOG2E * b1[t * 16 + c16];
        w2v[t] = W2[t * 16 + c16];
        w2loc += w2v[t];
    }
    const float Sconst = dpp_row_sum16(w2loc) + b2[0];   // valid at c16==15

    char* b0 = &xbuf[wv][0][0];
    char* b1_ = &xbuf[wv][1][0];
    char* b2_ = &xbuf[wv][2][0];

    const int gwave = blockIdx.x * WPB + wv;
    const int nwave = NBLK * WPB;     // 3072 waves, all resident

    float ls0 = 0.f, ls1 = 0.f;

    // ---- depth-2 prologue ----
    int tile = gwave;
    dma_tile(x + (size_t)tile * 1024, b0, lane);               // gwave < NTILES always
    if (tile + nwave < NTILES) {
        dma_tile(x + (size_t)(tile + nwave) * 1024, b1_, lane);
        asm volatile("s_waitcnt vmcnt(4)" ::: "memory");       // b0 landed, b1 in flight
    } else {
        asm volatile("s_waitcnt vmcnt(0)" ::: "memory");       // only b0 issued
    }

    // reader offsets (LINEAR layout): row c16 (256B), k-bytes g4*32 (+128)
    const int rb = c16 * 256 + g4 * 32;
    const int o0 = rb;          // k = g4*8 .. +3
    const int o1 = rb + 16;     // k = g4*8+4 .. +7
    const int o2 = rb + 128;    // k = 32+g4*8 .. +3
    const int o3 = rb + 144;    // k = 32+g4*8+4 .. +7

    for (; tile < NTILES; tile += nwave) {
        // b0 = landed current tile
        f32x4 a0 = *(const f32x4*)(b0 + o0);
        f32x4 a1 = *(const f32x4*)(b0 + o1);
        f32x4 a2 = *(const f32x4*)(b0 + o2);
        f32x4 a3 = *(const f32x4*)(b0 + o3);

        // f32 -> fp16 A-fragments
        half8 xf0, xf1;
        #pragma unroll
        for (int j = 0; j < 4; j++) {
            xf0[j]     = (_Float16)a0[j];
            xf0[4 + j] = (_Float16)a1[j];
            xf1[j]     = (_Float16)a2[j];
            xf1[4 + j] = (_Float16)a3[j];
        }

        // ---- h = x @ W1.T : 16 fp16 MFMAs, W from registers ----
        f32x4 acc[8];
        #pragma unroll
        for (int t = 0; t < 8; t++) acc[t] = (f32x4){0.f, 0.f, 0.f, 0.f};
        #pragma unroll
        for (int t = 0; t < 8; t++) {
            acc[t] = __builtin_amdgcn_mfma_f32_16x16x32_f16(xf0, wreg[t][0], acc[t], 0, 0, 0);
            acc[t] = __builtin_amdgcn_mfma_f32_16x16x32_f16(xf1, wreg[t][1], acc[t], 0, 0, 0);
        }

        // ---- epilogue: s = Sconst - 2*sum_j w2_j * rcp(exp2(2log2e*a_j + d1_j)+1)
        // C layout: lane holds h[row = g4*4 + r][col = t*16 + c16].
        float sp0 = 0.f, sp1 = 0.f, sp2 = 0.f, sp3 = 0.f;
        #pragma unroll
        for (int t = 0; t < 8; t++) {
            float r0 = __builtin_amdgcn_rcpf(EXP2F(fmaf(acc[t][0], TWO_LOG2E, d1v[t])) + 1.0f);
            float r1 = __builtin_amdgcn_rcpf(EXP2F(fmaf(acc[t][1], TWO_LOG2E, d1v[t])) + 1.0f);
            float r2 = __builtin_amdgcn_rcpf(EXP2F(fmaf(acc[t][2], TWO_LOG2E, d1v[t])) + 1.0f);
            float r3 = __builtin_amdgcn_rcpf(EXP2F(fmaf(acc[t][3], TWO_LOG2E, d1v[t])) + 1.0f);
            sp0 = fmaf(w2v[t], r0, sp0);
            sp1 = fmaf(w2v[t], r1, sp1);
            sp2 = fmaf(w2v[t], r2, sp2);
            sp3 = fmaf(w2v[t], r3, sp3);
        }
        sp0 = dpp_row_sum16(sp0);
        sp1 = dpp_row_sum16(sp1);
        sp2 = dpp_row_sum16(sp2);
        sp3 = dpp_row_sum16(sp3);

        if (c16 == 15) {   // 4 lanes/wave, each owns 4 consecutive rows
            const int row0 = tile * 16 + g4 * 4;
            int4 t4 = *(const int4*)&T[row0];
            float e0 = EXP2F(fmaf(-2.0f * sp0, LOG2E, Sconst * LOG2E));
            float e1 = EXP2F(fmaf(-2.0f * sp1, LOG2E, Sconst * LOG2E));
            float e2 = EXP2F(fmaf(-2.0f * sp2, LOG2E, Sconst * LOG2E));
            float e3 = EXP2F(fmaf(-2.0f * sp3, LOG2E, Sconst * LOG2E));
            *(f32x4*)&e_out[row0] = (f32x4){e0, e1, e2, e3};
            if (t4.x == 0) ls0 += e0; else ls1 += e0;
            if (t4.y == 0) ls0 += e1; else ls1 += e1;
            if (t4.z == 0) ls0 += e2; else ls1 += e2;
            if (t4.w == 0) ls0 += e3; else ls1 += e3;
        }

        // ---- issue DMA for tile+2 into the free buffer, then counted wait ----
        const int nt2 = tile + 2 * nwave;
        if (nt2 < NTILES) {
            dma_tile(x + (size_t)nt2 * 1024, b2_, lane);
            // keep {store, 4 new DMA} in flight; forces tile+1's DMA landed
            asm volatile("s_waitcnt vmcnt(5)" ::: "memory");
        } else {
            // tail: nothing new issued; force tile+1's DMA landed (keep store)
            asm volatile("s_waitcnt vmcnt(1)" ::: "memory");
        }

        // rotate triple buffer
        char* tmp = b0; b0 = b1_; b1_ = b2_; b2_ = tmp;
    }

    // per-wave reduce, then one atomic pair per wave (3072 waves total)
    #pragma unroll
    for (int off = 32; off > 0; off >>= 1) {
        ls0 += __shfl_down(ls0, off, 64);
        ls1 += __shfl_down(ls1, off, 64);
    }
    if (lane == 0) {
        atomicAdd(&gsums[0], ls0);
        atomicAdd(&gsums[1], ls1);
    }
}

__global__ __launch_bounds__(256) void normalize_kernel(
    float* __restrict__ e_out, const int* __restrict__ T,
    const float* __restrict__ gsums)
{
    const float inv0 = 1.0f / gsums[0];
    const float inv1 = 1.0f / gsums[1];
    const int n4 = NROWS / 4;
    const int stride = gridDim.x * blockDim.x;
    for (int i = blockIdx.x * blockDim.x + threadIdx.x; i < n4; i += stride) {
        float4 e = reinterpret_cast<const float4*>(e_out)[i];
        int4  t = reinterpret_cast<const int4*>(T)[i];
        e.x *= (t.x == 0) ? inv0 : inv1;
        e.y *= (t.y == 0) ? inv0 : inv1;
        e.z *= (t.z == 0) ? inv0 : inv1;
        e.w *= (t.w == 0) ? inv0 : inv1;
        reinterpret_cast<float4*>(e_out)[i] = e;
    }
}

extern "C" void kernel_launch(void* const* d_in, const int* in_sizes, int n_in,
                              void* d_out, int out_size, void* d_ws, size_t ws_size,
                              hipStream_t stream) {
    const float* x  = (const float*)d_in[0];
    const int*   T  = (const int*)d_in[1];
    const float* W1 = (const float*)d_in[2];
    const float* b1 = (const float*)d_in[3];
    const float* W2 = (const float*)d_in[4];
    const float* b2 = (const float*)d_in[5];
    float* e_out = (float*)d_out;
    float* gsums = (float*)d_ws;

    zero_sums_kernel<<<1, 64, 0, stream>>>(gsums);

    // 768 blocks x 256 thr = 3072 waves; 48 KB LDS, ~150 VGPR ->
    // 3 blocks/CU, 12 waves/CU (3/SIMD), all resident.
    fused_mfma_kernel<<<NBLK, BLOCK, 0, stream>>>(x, T, W1, b1, W2, b2, e_out, gsums);

    normalize_kernel<<<2048, 256, 0, stream>>>(e_out, T, gsums);
}